// Round 3
// baseline (702.109 us; speedup 1.0000x reference)
//
#include <hip/hip_runtime.h>
#include <cstddef>

#define B_ 2
#define S_ 2048
#define E_ 768
#define H_ 12
#define D_ 64
#define M_ (B_*S_)   // 4096 rows of x

typedef float f4 __attribute__((ext_vector_type(4)));
typedef short short4v __attribute__((ext_vector_type(4)));
typedef short short8 __attribute__((ext_vector_type(8)));

// fp32 -> bf16 (RNE, bit pattern as short)
__device__ __forceinline__ short f2bf(float f) {
    union { float f; unsigned u; } v; v.f = f;
    unsigned r = (v.u + 0x7fffu + ((v.u >> 16) & 1u)) >> 16;
    return (short)r;
}

// ---------------------------------------------------------------------------
// Async stage of a 64-row x 64-col bf16 tile into LDS [64][8 short8 chunks],
// swizzled content [r][cc ^ (r&7)] (source-pre-swizzle, linear LDS dest).
// Used by the GEMM only.
// ---------------------------------------------------------------------------
__device__ __forceinline__ void stage64(const short* __restrict__ g0, int rstride,
                                        short8* lds, int w, int lane)
{
    #pragma unroll
    for (int i = 0; i < 2; ++i) {
        const int n = w * 128 + i * 64 + lane;
        const int r = n >> 3, s = n & 7;
        const int cc = s ^ (r & 7);
        const short* src = g0 + (size_t)r * rstride + cc * 8;
        __builtin_amdgcn_global_load_lds(
            (const __attribute__((address_space(1))) unsigned int*)src,
            (__attribute__((address_space(3))) unsigned int*)(lds + w * 128 + i * 64),
            16, 0, 0);
    }
}

// ---------------------------------------------------------------------------
// Prep 1: fp32 -> bf16 elementwise (x -> xb). 8 elems/thread, coalesced.
// ---------------------------------------------------------------------------
__global__ __launch_bounds__(256) void cvt_bf16_k(const float* __restrict__ in,
                                                  short* __restrict__ out, int n8)
{
    int i = blockIdx.x * 256 + threadIdx.x;
    if (i >= n8) return;
    f4 a = *(const f4*)(in + (size_t)i * 8);
    f4 b = *(const f4*)(in + (size_t)i * 8 + 4);
    short8 o;
    o[0] = f2bf(a[0]); o[1] = f2bf(a[1]); o[2] = f2bf(a[2]); o[3] = f2bf(a[3]);
    o[4] = f2bf(b[0]); o[5] = f2bf(b[1]); o[6] = f2bf(b[2]); o[7] = f2bf(b[3]);
    *(short8*)(out + (size_t)i * 8) = o;
}

// ---------------------------------------------------------------------------
// Prep 2: W[k][n] fp32 -> Wt[n][k] bf16, all four weight matrices (z-select).
// ---------------------------------------------------------------------------
__global__ __launch_bounds__(256) void wtrans_k(const float* __restrict__ Wq,
                                                const float* __restrict__ Wk,
                                                const float* __restrict__ Wv,
                                                const float* __restrict__ Wo,
                                                short* __restrict__ Wt)
{
    __shared__ float T[32][33];
    const float* W = (blockIdx.z == 0) ? Wq : (blockIdx.z == 1) ? Wk
                   : (blockIdx.z == 2) ? Wv : Wo;
    short* o = Wt + (size_t)blockIdx.z * E_ * E_;
    const int tx = threadIdx.x & 31, ty = threadIdx.x >> 5;   // ty 0..7
    const int k0 = blockIdx.y * 32, n0 = blockIdx.x * 32;
    #pragma unroll
    for (int i = 0; i < 4; ++i)
        T[ty * 4 + i][tx] = W[(size_t)(k0 + ty * 4 + i) * E_ + n0 + tx];
    __syncthreads();
    #pragma unroll
    for (int i = 0; i < 4; ++i)
        o[(size_t)(n0 + ty * 4 + i) * E_ + k0 + tx] = f2bf(T[tx][ty * 4 + i]);
}

// ---------------------------------------------------------------------------
// bf16 MFMA GEMM (unchanged from R2): 2-phase dbuf gload_lds staging,
// 64x64 tile, 4 waves. out = A[M,768](bf16) @ Wt[n][k](bf16) + bias.
// MODE 0: fp32 [M,768]; MODE 1: bf16 [B,H,S,D]*scale; MODE 2: bf16 [B,H,D,S].
// ---------------------------------------------------------------------------
template<int MODE>
__global__ __launch_bounds__(256) void gemm_mfma_k(
    const short* __restrict__ A, const short* __restrict__ Bt,
    const float* __restrict__ bias, float* __restrict__ outf,
    short* __restrict__ outb, float scale)
{
    __shared__ short8 As[2][64][8];   // 16 KB
    __shared__ short8 Bs[2][64][8];   // 16 KB
    const int t = threadIdx.x;
    const int w = t >> 6, lane = t & 63, ln = lane & 15, quad = lane >> 4;
    const int m0 = blockIdx.y * 64, n0 = blockIdx.x * 64;

    const short* Ab = A  + (size_t)m0 * E_;  // row stride E_
    const short* Bb = Bt + (size_t)n0 * E_;

    f4 acc[4];
    #pragma unroll
    for (int i = 0; i < 4; ++i) acc[i] = (f4){0.f, 0.f, 0.f, 0.f};

    stage64(Ab, E_, &As[0][0][0], w, lane);
    stage64(Bb, E_, &Bs[0][0][0], w, lane);
    __syncthreads();                          // vmcnt(0) drain: tile 0 ready

    int cb = 0;
    for (int k0 = 0; k0 < E_; k0 += 64) {
        if (k0 + 64 < E_) {
            stage64(Ab + k0 + 64, E_, &As[cb ^ 1][0][0], w, lane);
            stage64(Bb + k0 + 64, E_, &Bs[cb ^ 1][0][0], w, lane);
        }
        const int ar = w * 16 + ln;
        short8 af0 = As[cb][ar][quad ^ (ar & 7)];
        short8 af1 = As[cb][ar][(quad + 4) ^ (ar & 7)];
        #pragma unroll
        for (int ng = 0; ng < 4; ++ng) {
            int br = ng * 16 + ln;
            short8 bf0 = Bs[cb][br][quad ^ (br & 7)];
            short8 bf1 = Bs[cb][br][(quad + 4) ^ (br & 7)];
            acc[ng] = __builtin_amdgcn_mfma_f32_16x16x32_bf16(af0, bf0, acc[ng], 0, 0, 0);
            acc[ng] = __builtin_amdgcn_mfma_f32_16x16x32_bf16(af1, bf1, acc[ng], 0, 0, 0);
        }
        __syncthreads();
        cb ^= 1;
    }

    #pragma unroll
    for (int ng = 0; ng < 4; ++ng) {
        int c = n0 + ng * 16 + ln;
        float bv = bias[c];
        #pragma unroll
        for (int g = 0; g < 4; ++g) {
            int r = m0 + w * 16 + quad * 4 + g;
            float v = acc[ng][g] + bv;
            if (MODE == 0) {
                outf[(size_t)r * E_ + c] = v;
            } else {
                int b = r >> 11, s = r & (S_ - 1);
                int h = c >> 6,  d = c & (D_ - 1);
                if (MODE == 1)
                    outb[((size_t)(b * H_ + h) * S_ + s) * D_ + d] = f2bf(v * scale);
                else
                    outb[((size_t)(b * H_ + h) * D_ + d) * S_ + s] = f2bf(v);
            }
        }
    }
}

// ---------------------------------------------------------------------------
// MFMA flash attention, BARRIER-FREE. Block = 256 thr (4 independent waves),
// 64 q-rows (16/wave), one (b,h). K/V per head = 512 KB -> L2-resident:
// fragments are read DIRECTLY from global (no LDS staging, no __syncthreads,
// no vmcnt drains; P stores retire in background).
// Swapped QK^T: mfma(kf, qf) -> D[k-local = quad*4+g][q = ln]. Each lane
// holds 4 consecutive k for one q-row, so:
//   - P writes are packed f4 (64B-coalesced per 4-quad row group)
//   - PT writes are packed ds_write_b64
//   - l reduces with 2 shfl_xor (quads); inv_l lands per-q-row in-lane.
// Pass 1: l = sum exp(s-8) (fixed base, exact). Pass 2: recompute scores,
// write normalized P (fp32) + P@V via wave-private PT round-trip (lgkmcnt
// orders it, no barrier).
// ---------------------------------------------------------------------------
__global__ __launch_bounds__(256) void attn_k(
    const short* __restrict__ Qb, const short* __restrict__ Kb,
    const short* __restrict__ Vt, float* __restrict__ P,
    short* __restrict__ ctxb)
{
    __shared__ short PT[4][16][72]; // per-wave P tile, stride 72 (16B-aligned)

    const int t    = threadIdx.x;
    const int w    = t >> 6;
    const int lane = t & 63, ln = lane & 15, quad = lane >> 4;
    const int bh   = blockIdx.y;
    const int qr   = blockIdx.x * 64 + w * 16;   // wave's first q row

    const size_t kvbase = (size_t)bh * S_ * D_;  // also == bh*D_*S_ for Vt
    const short* Kp = Kb + kvbase;               // [S][D]
    const short* Vp = Vt + kvbase;               // [D][S]

    // Q B-fragments (Q pre-scaled by 1/8): lane holds Q[qr+ln][quad*8+j (+32)]
    short8 qf0, qf1;
    {
        const short* qrow = Qb + kvbase + (size_t)(qr + ln) * D_;
        qf0 = *(const short8*)(qrow + quad * 8);
        qf1 = *(const short8*)(qrow + 32 + quad * 8);
    }

    // ---- pass 1: l = sum_k exp(s - 8), per lane for q-row (qr+ln) ----
    float l_acc = 0.f;
    for (int k0 = 0; k0 < S_; k0 += 64) {
        #pragma unroll
        for (int kg = 0; kg < 4; ++kg) {
            const short* krow = Kp + (size_t)(k0 + kg * 16 + ln) * D_;
            short8 kf0 = *(const short8*)(krow + quad * 8);
            short8 kf1 = *(const short8*)(krow + 32 + quad * 8);
            f4 sc = {0.f, 0.f, 0.f, 0.f};
            sc = __builtin_amdgcn_mfma_f32_16x16x32_bf16(kf0, qf0, sc, 0, 0, 0);
            sc = __builtin_amdgcn_mfma_f32_16x16x32_bf16(kf1, qf1, sc, 0, 0, 0);
            #pragma unroll
            for (int g = 0; g < 4; ++g) l_acc += __expf(sc[g] - 8.0f);
        }
    }
    // reduce over the 4 quads (lanes ln, ln+16, ln+32, ln+48 share q-row ln)
    l_acc += __shfl_xor(l_acc, 16, 64);
    l_acc += __shfl_xor(l_acc, 32, 64);
    const float inv_l = 1.0f / l_acc;            // for q-row qr+ln, in-lane

    f4 acc[4];
    #pragma unroll
    for (int dg = 0; dg < 4; ++dg) acc[dg] = (f4){0.f, 0.f, 0.f, 0.f};

    float* Pw = P + ((size_t)bh * S_ + qr + ln) * S_;   // lane's q-row

    // ---- pass 2: normalized P out + P@V ----
    for (int k0 = 0; k0 < S_; k0 += 64) {
        #pragma unroll
        for (int kg = 0; kg < 4; ++kg) {
            const short* krow = Kp + (size_t)(k0 + kg * 16 + ln) * D_;
            short8 kf0 = *(const short8*)(krow + quad * 8);
            short8 kf1 = *(const short8*)(krow + 32 + quad * 8);
            f4 sc = {0.f, 0.f, 0.f, 0.f};
            sc = __builtin_amdgcn_mfma_f32_16x16x32_bf16(kf0, qf0, sc, 0, 0, 0);
            sc = __builtin_amdgcn_mfma_f32_16x16x32_bf16(kf1, qf1, sc, 0, 0, 0);
            f4 p; short4v pb;
            #pragma unroll
            for (int g = 0; g < 4; ++g) {
                p[g]  = __expf(sc[g] - 8.0f) * inv_l;
                pb[g] = f2bf(p[g]);
            }
            // k = k0 + kg*16 + quad*4 + g : 4 consecutive -> packed stores
            *(f4*)(Pw + k0 + kg * 16 + quad * 4) = p;
            *(short4v*)&PT[w][ln][kg * 16 + quad * 4] = pb;
        }
        // PT[w] is wave-private: ds_write -> ds_read ordered by lgkmcnt
        short8 af0 = *(const short8*)&PT[w][ln][quad * 8];
        short8 af1 = *(const short8*)&PT[w][ln][32 + quad * 8];
        #pragma unroll
        for (int dg = 0; dg < 4; ++dg) {
            const short* vrow = Vp + (size_t)(dg * 16 + ln) * S_ + k0;
            short8 vf0 = *(const short8*)(vrow + quad * 8);
            short8 vf1 = *(const short8*)(vrow + 32 + quad * 8);
            acc[dg] = __builtin_amdgcn_mfma_f32_16x16x32_bf16(af0, vf0, acc[dg], 0, 0, 0);
            acc[dg] = __builtin_amdgcn_mfma_f32_16x16x32_bf16(af1, vf1, acc[dg], 0, 0, 0);
        }
    }

    // ctx in bf16 [B,S,E] so the output projection is a bf16 MFMA GEMM
    const int b = bh / H_, h = bh % H_;
    #pragma unroll
    for (int dg = 0; dg < 4; ++dg)
        #pragma unroll
        for (int g = 0; g < 4; ++g)
            ctxb[(size_t)(b * S_ + qr + quad * 4 + g) * E_ + h * D_ + dg * 16 + ln]
                = f2bf(acc[dg][g]);
}

// ---------------------------------------------------------------------------
extern "C" void kernel_launch(void* const* d_in, const int* in_sizes, int n_in,
                              void* d_out, int out_size, void* d_ws, size_t ws_size,
                              hipStream_t stream) {
    const float* x  = (const float*)d_in[0];
    const float* Wq = (const float*)d_in[1];
    const float* bq = (const float*)d_in[2];
    const float* Wk = (const float*)d_in[3];
    const float* bk = (const float*)d_in[4];
    const float* Wv = (const float*)d_in[5];
    const float* bv = (const float*)d_in[6];
    const float* Wo = (const float*)d_in[7];
    const float* bo = (const float*)d_in[8];

    const size_t NE = (size_t)M_ * E_;       // 3,145,728
    const size_t W2 = (size_t)E_ * E_;       // 589,824
    short* xb  = (short*)d_ws;               // bf16 x       [M,768]
    short* Wt  = xb + NE;                    // bf16 Wt[4]   [768 n][768 k]
    short* Qb  = Wt + 4 * W2;                // bf16 [B,H,S,D], pre-scaled 1/8
    short* Kb  = Qb + NE;                    // bf16 [B,H,S,D]
    short* Vtb = Kb + NE;                    // bf16 [B,H,D,S]
    short* Cb  = Vtb + NE;                   // bf16 ctx [B,S,E]

    float* out0  = (float*)d_out;            // [B,S,E]
    float* attnw = out0 + NE;                // [B,H,S,S]

    cvt_bf16_k<<<dim3((int)(NE / 8 / 256)), 256, 0, stream>>>(x, xb, (int)(NE / 8));
    wtrans_k<<<dim3(24, 24, 4), 256, 0, stream>>>(Wq, Wk, Wv, Wo, Wt);

    dim3 gg(E_ / 64, M_ / 64);               // (12, 64)
    gemm_mfma_k<1><<<gg, 256, 0, stream>>>(xb, Wt + 0 * W2, bq, nullptr, Qb, 0.125f);
    gemm_mfma_k<1><<<gg, 256, 0, stream>>>(xb, Wt + 1 * W2, bk, nullptr, Kb, 1.0f);
    gemm_mfma_k<2><<<gg, 256, 0, stream>>>(xb, Wt + 2 * W2, bv, nullptr, Vtb, 1.0f);
    attn_k<<<dim3(S_ / 64, B_ * H_), 256, 0, stream>>>(Qb, Kb, Vtb, attnw, Cb);
    gemm_mfma_k<0><<<gg, 256, 0, stream>>>(Cb, Wt + 3 * W2, bo, out0, nullptr, 1.0f);
}

// Round 4
// 548.201 us; speedup vs baseline: 1.2808x; 1.2808x over previous
//
#include <hip/hip_runtime.h>
#include <cstddef>

#define B_ 2
#define S_ 2048
#define E_ 768
#define H_ 12
#define D_ 64
#define M_ (B_*S_)   // 4096 rows of x

typedef float f4 __attribute__((ext_vector_type(4)));
typedef short short4v __attribute__((ext_vector_type(4)));
typedef short short8 __attribute__((ext_vector_type(8)));

// fp32 -> bf16 (RNE, bit pattern as short)
__device__ __forceinline__ short f2bf(float f) {
    union { float f; unsigned u; } v; v.f = f;
    unsigned r = (v.u + 0x7fffu + ((v.u >> 16) & 1u)) >> 16;
    return (short)r;
}

// counted waitcnt + raw barrier (m201-verified pattern)
#define VMCNT(n) asm volatile("s_waitcnt vmcnt(" #n ")" ::: "memory")
#define BAR()    __builtin_amdgcn_s_barrier()

// ---------------------------------------------------------------------------
// Async stage of a 64-row x 64-col bf16 tile into LDS [64][8 short8 chunks],
// swizzled content [r][cc ^ (r&7)] (source-pre-swizzle, linear LDS dest).
// Per wave: 2 gload_lds (wave w covers slots [w*128, w*128+128)).
// ---------------------------------------------------------------------------
__device__ __forceinline__ void stage64(const short* __restrict__ g0, int rstride,
                                        short8* lds, int w, int lane)
{
    #pragma unroll
    for (int i = 0; i < 2; ++i) {
        const int n = w * 128 + i * 64 + lane;
        const int r = n >> 3, s = n & 7;
        const int cc = s ^ (r & 7);
        const short* src = g0 + (size_t)r * rstride + cc * 8;
        __builtin_amdgcn_global_load_lds(
            (const __attribute__((address_space(1))) unsigned int*)src,
            (__attribute__((address_space(3))) unsigned int*)(lds + w * 128 + i * 64),
            16, 0, 0);
    }
}

// ---------------------------------------------------------------------------
// Prep 1: fp32 -> bf16 elementwise (x -> xb). 8 elems/thread, coalesced.
// ---------------------------------------------------------------------------
__global__ __launch_bounds__(256) void cvt_bf16_k(const float* __restrict__ in,
                                                  short* __restrict__ out, int n8)
{
    int i = blockIdx.x * 256 + threadIdx.x;
    if (i >= n8) return;
    f4 a = *(const f4*)(in + (size_t)i * 8);
    f4 b = *(const f4*)(in + (size_t)i * 8 + 4);
    short8 o;
    o[0] = f2bf(a[0]); o[1] = f2bf(a[1]); o[2] = f2bf(a[2]); o[3] = f2bf(a[3]);
    o[4] = f2bf(b[0]); o[5] = f2bf(b[1]); o[6] = f2bf(b[2]); o[7] = f2bf(b[3]);
    *(short8*)(out + (size_t)i * 8) = o;
}

// ---------------------------------------------------------------------------
// Prep 2: W[k][n] fp32 -> Wt[n][k] bf16, all four weight matrices (z-select).
// ---------------------------------------------------------------------------
__global__ __launch_bounds__(256) void wtrans_k(const float* __restrict__ Wq,
                                                const float* __restrict__ Wk,
                                                const float* __restrict__ Wv,
                                                const float* __restrict__ Wo,
                                                short* __restrict__ Wt)
{
    __shared__ float T[32][33];
    const float* W = (blockIdx.z == 0) ? Wq : (blockIdx.z == 1) ? Wk
                   : (blockIdx.z == 2) ? Wv : Wo;
    short* o = Wt + (size_t)blockIdx.z * E_ * E_;
    const int tx = threadIdx.x & 31, ty = threadIdx.x >> 5;   // ty 0..7
    const int k0 = blockIdx.y * 32, n0 = blockIdx.x * 32;
    #pragma unroll
    for (int i = 0; i < 4; ++i)
        T[ty * 4 + i][tx] = W[(size_t)(k0 + ty * 4 + i) * E_ + n0 + tx];
    __syncthreads();
    #pragma unroll
    for (int i = 0; i < 4; ++i)
        o[(size_t)(n0 + ty * 4 + i) * E_ + k0 + tx] = f2bf(T[tx][ty * 4 + i]);
}

// ---------------------------------------------------------------------------
// bf16 MFMA GEMM (unchanged): 2-phase dbuf gload_lds staging, 64x64 tile,
// 4 waves. out = A[M,768](bf16) @ Wt[n][k](bf16) + bias.
// MODE 0: fp32 [M,768]; MODE 1: bf16 [B,H,S,D]*scale; MODE 2: bf16 [B,H,D,S].
// ---------------------------------------------------------------------------
template<int MODE>
__global__ __launch_bounds__(256) void gemm_mfma_k(
    const short* __restrict__ A, const short* __restrict__ Bt,
    const float* __restrict__ bias, float* __restrict__ outf,
    short* __restrict__ outb, float scale)
{
    __shared__ short8 As[2][64][8];   // 16 KB
    __shared__ short8 Bs[2][64][8];   // 16 KB
    const int t = threadIdx.x;
    const int w = t >> 6, lane = t & 63, ln = lane & 15, quad = lane >> 4;
    const int m0 = blockIdx.y * 64, n0 = blockIdx.x * 64;

    const short* Ab = A  + (size_t)m0 * E_;  // row stride E_
    const short* Bb = Bt + (size_t)n0 * E_;

    f4 acc[4];
    #pragma unroll
    for (int i = 0; i < 4; ++i) acc[i] = (f4){0.f, 0.f, 0.f, 0.f};

    stage64(Ab, E_, &As[0][0][0], w, lane);
    stage64(Bb, E_, &Bs[0][0][0], w, lane);
    __syncthreads();                          // vmcnt(0) drain: tile 0 ready

    int cb = 0;
    for (int k0 = 0; k0 < E_; k0 += 64) {
        if (k0 + 64 < E_) {
            stage64(Ab + k0 + 64, E_, &As[cb ^ 1][0][0], w, lane);
            stage64(Bb + k0 + 64, E_, &Bs[cb ^ 1][0][0], w, lane);
        }
        const int ar = w * 16 + ln;
        short8 af0 = As[cb][ar][quad ^ (ar & 7)];
        short8 af1 = As[cb][ar][(quad + 4) ^ (ar & 7)];
        #pragma unroll
        for (int ng = 0; ng < 4; ++ng) {
            int br = ng * 16 + ln;
            short8 bf0 = Bs[cb][br][quad ^ (br & 7)];
            short8 bf1 = Bs[cb][br][(quad + 4) ^ (br & 7)];
            acc[ng] = __builtin_amdgcn_mfma_f32_16x16x32_bf16(af0, bf0, acc[ng], 0, 0, 0);
            acc[ng] = __builtin_amdgcn_mfma_f32_16x16x32_bf16(af1, bf1, acc[ng], 0, 0, 0);
        }
        __syncthreads();
        cb ^= 1;
    }

    #pragma unroll
    for (int ng = 0; ng < 4; ++ng) {
        int c = n0 + ng * 16 + ln;
        float bv = bias[c];
        #pragma unroll
        for (int g = 0; g < 4; ++g) {
            int r = m0 + w * 16 + quad * 4 + g;
            float v = acc[ng][g] + bv;
            if (MODE == 0) {
                outf[(size_t)r * E_ + c] = v;
            } else {
                int b = r >> 11, s = r & (S_ - 1);
                int h = c >> 6,  d = c & (D_ - 1);
                if (MODE == 1)
                    outb[((size_t)(b * H_ + h) * S_ + s) * D_ + d] = f2bf(v * scale);
                else
                    outb[((size_t)(b * H_ + h) * D_ + d) * S_ + s] = f2bf(v);
            }
        }
    }
}

// ---------------------------------------------------------------------------
// MFMA flash attention: LDS-staged K/V (dbuf) + swapped QK^T + counted-vmcnt
// barriers + XCD head-grouping swizzle.
//   * Swapped QK^T: mfma(kf, qf) -> lane holds 4 consecutive k of ONE q-row
//     (q = ln). P stores are packed f4; PT writes are b64; l reduces with
//     2 shfl_xor; inv_l lands per-q-row in-lane. (Proven in R3.)
//   * Staging: stage(t+1) issued at top of tile t; raw s_barrier with
//     s_waitcnt vmcnt(4) -> the 4 stage loads (older) are complete, the 4
//     P stores (newer) float across the barrier and drain under compute.
//     Pass 1 has no stores -> vmcnt(0). No __syncthreads anywhere.
//   * Swizzle: 1-D grid 768; xcd=orig&7; lin=xcd*96+(orig>>3); bh=lin>>5,
//     qb=lin&31 -> each XCD serves exactly 3 heads (1.5 MB K+V, L2-fit).
// Pass 1: l = sum exp(s-8) (fixed base, exact). Pass 2: recompute scores,
// packed normalized-P stores + P@V via wave-private PT round-trip (lgkmcnt
// orders it; PT untouched by barriers).
// ---------------------------------------------------------------------------
__global__ __launch_bounds__(256) void attn_k(
    const short* __restrict__ Qb, const short* __restrict__ Kb,
    const short* __restrict__ Vt, float* __restrict__ P,
    short* __restrict__ ctxb)
{
    __shared__ short8 KT[2][64][8];  // 16 KB, [key][d-chunk] swizzled
    __shared__ short8 VT[2][64][8];  // 16 KB, [d][key-chunk] swizzled
    __shared__ short  PT[4][16][72]; // per-wave P tile, stride 72

    const int t    = threadIdx.x;
    const int w    = t >> 6;
    const int lane = t & 63, ln = lane & 15, quad = lane >> 4;

    // XCD head-grouping swizzle (768 blocks, 8 XCDs, 96 blocks/XCD = 3 heads)
    const int orig = blockIdx.x;
    const int lin  = (orig & 7) * 96 + (orig >> 3);
    const int bh   = lin >> 5;
    const int qb   = lin & 31;
    const int qr   = qb * 64 + w * 16;           // wave's first q row

    const size_t kvbase = (size_t)bh * S_ * D_;  // also == bh*D_*S_ for Vt
    const short* Kp = Kb + kvbase;               // [S][D]
    const short* Vp = Vt + kvbase;               // [D][S]

    // Q fragments (Q pre-scaled by 1/8): lane holds Q[qr+ln][quad*8+j (+32)]
    short8 qf0, qf1;
    {
        const short* qrow = Qb + kvbase + (size_t)(qr + ln) * D_;
        qf0 = *(const short8*)(qrow + quad * 8);
        qf1 = *(const short8*)(qrow + 32 + quad * 8);
    }

    // ---- pass 1: l = sum_k exp(s - 8), per lane for q-row (qr+ln) ----
    float l_acc = 0.f;
    stage64(Kp, D_, &KT[0][0][0], w, lane);
    VMCNT(0); BAR();
    int cb = 0;
    for (int k0 = 0; k0 < S_; k0 += 64) {
        if (k0 + 64 < S_)
            stage64(Kp + (size_t)(k0 + 64) * D_, D_, &KT[cb ^ 1][0][0], w, lane);
        #pragma unroll
        for (int kg = 0; kg < 4; ++kg) {
            int row = kg * 16 + ln;
            short8 kf0 = KT[cb][row][quad ^ (row & 7)];
            short8 kf1 = KT[cb][row][(quad + 4) ^ (row & 7)];
            f4 sc = {0.f, 0.f, 0.f, 0.f};
            sc = __builtin_amdgcn_mfma_f32_16x16x32_bf16(kf0, qf0, sc, 0, 0, 0);
            sc = __builtin_amdgcn_mfma_f32_16x16x32_bf16(kf1, qf1, sc, 0, 0, 0);
            #pragma unroll
            for (int g = 0; g < 4; ++g) l_acc += __expf(sc[g] - 8.0f);
        }
        VMCNT(0); BAR();
        cb ^= 1;
    }
    // reduce over the 4 quads (lanes ln, ln+16, ln+32, ln+48 share q-row ln)
    l_acc += __shfl_xor(l_acc, 16, 64);
    l_acc += __shfl_xor(l_acc, 32, 64);
    const float inv_l = 1.0f / l_acc;            // for q-row qr+ln, in-lane

    f4 acc[4];
    #pragma unroll
    for (int dg = 0; dg < 4; ++dg) acc[dg] = (f4){0.f, 0.f, 0.f, 0.f};

    float* Pw = P + ((size_t)bh * S_ + qr + ln) * S_;   // lane's q-row

    // ---- pass 2: packed normalized P out + P@V ----
    stage64(Kp, D_, &KT[0][0][0], w, lane);
    stage64(Vp, S_, &VT[0][0][0], w, lane);
    VMCNT(0); BAR();
    cb = 0;
    for (int k0 = 0; k0 < S_; k0 += 64) {
        if (k0 + 64 < S_) {
            stage64(Kp + (size_t)(k0 + 64) * D_, D_, &KT[cb ^ 1][0][0], w, lane);
            stage64(Vp + k0 + 64,                S_, &VT[cb ^ 1][0][0], w, lane);
        }
        #pragma unroll
        for (int kg = 0; kg < 4; ++kg) {
            int row = kg * 16 + ln;
            short8 kf0 = KT[cb][row][quad ^ (row & 7)];
            short8 kf1 = KT[cb][row][(quad + 4) ^ (row & 7)];
            f4 sc = {0.f, 0.f, 0.f, 0.f};
            sc = __builtin_amdgcn_mfma_f32_16x16x32_bf16(kf0, qf0, sc, 0, 0, 0);
            sc = __builtin_amdgcn_mfma_f32_16x16x32_bf16(kf1, qf1, sc, 0, 0, 0);
            f4 p; short4v pb;
            #pragma unroll
            for (int g = 0; g < 4; ++g) {
                p[g]  = __expf(sc[g] - 8.0f) * inv_l;
                pb[g] = f2bf(p[g]);
            }
            // k = k0 + kg*16 + quad*4 + g : 4 consecutive -> packed stores
            *(f4*)(Pw + k0 + kg * 16 + quad * 4) = p;
            *(short4v*)&PT[w][ln][kg * 16 + quad * 4] = pb;
        }
        // PT[w] is wave-private: ds_write -> ds_read ordered by lgkmcnt
        short8 af0 = *(const short8*)&PT[w][ln][quad * 8];
        short8 af1 = *(const short8*)&PT[w][ln][32 + quad * 8];
        #pragma unroll
        for (int dg = 0; dg < 4; ++dg) {
            int row = dg * 16 + ln;
            short8 vf0 = VT[cb][row][quad ^ (row & 7)];
            short8 vf1 = VT[cb][row][(quad + 4) ^ (row & 7)];
            acc[dg] = __builtin_amdgcn_mfma_f32_16x16x32_bf16(af0, vf0, acc[dg], 0, 0, 0);
            acc[dg] = __builtin_amdgcn_mfma_f32_16x16x32_bf16(af1, vf1, acc[dg], 0, 0, 0);
        }
        // stage loads (older) complete; the 4 P stores (newer) float across
        VMCNT(4); BAR();
        cb ^= 1;
    }

    // ctx in bf16 [B,S,E] so the output projection is a bf16 MFMA GEMM
    const int b = bh / H_, h = bh % H_;
    #pragma unroll
    for (int dg = 0; dg < 4; ++dg)
        #pragma unroll
        for (int g = 0; g < 4; ++g)
            ctxb[(size_t)(b * S_ + qr + quad * 4 + g) * E_ + h * D_ + dg * 16 + ln]
                = f2bf(acc[dg][g]);
}

// ---------------------------------------------------------------------------
extern "C" void kernel_launch(void* const* d_in, const int* in_sizes, int n_in,
                              void* d_out, int out_size, void* d_ws, size_t ws_size,
                              hipStream_t stream) {
    const float* x  = (const float*)d_in[0];
    const float* Wq = (const float*)d_in[1];
    const float* bq = (const float*)d_in[2];
    const float* Wk = (const float*)d_in[3];
    const float* bk = (const float*)d_in[4];
    const float* Wv = (const float*)d_in[5];
    const float* bv = (const float*)d_in[6];
    const float* Wo = (const float*)d_in[7];
    const float* bo = (const float*)d_in[8];

    const size_t NE = (size_t)M_ * E_;       // 3,145,728
    const size_t W2 = (size_t)E_ * E_;       // 589,824
    short* xb  = (short*)d_ws;               // bf16 x       [M,768]
    short* Wt  = xb + NE;                    // bf16 Wt[4]   [768 n][768 k]
    short* Qb  = Wt + 4 * W2;                // bf16 [B,H,S,D], pre-scaled 1/8
    short* Kb  = Qb + NE;                    // bf16 [B,H,S,D]
    short* Vtb = Kb + NE;                    // bf16 [B,H,D,S]
    short* Cb  = Vtb + NE;                   // bf16 ctx [B,S,E]

    float* out0  = (float*)d_out;            // [B,S,E]
    float* attnw = out0 + NE;                // [B,H,S,S]

    cvt_bf16_k<<<dim3((int)(NE / 8 / 256)), 256, 0, stream>>>(x, xb, (int)(NE / 8));
    wtrans_k<<<dim3(24, 24, 4), 256, 0, stream>>>(Wq, Wk, Wv, Wo, Wt);

    dim3 gg(E_ / 64, M_ / 64);               // (12, 64)
    gemm_mfma_k<1><<<gg, 256, 0, stream>>>(xb, Wt + 0 * W2, bq, nullptr, Qb, 0.125f);
    gemm_mfma_k<1><<<gg, 256, 0, stream>>>(xb, Wt + 1 * W2, bk, nullptr, Kb, 1.0f);
    gemm_mfma_k<2><<<gg, 256, 0, stream>>>(xb, Wt + 2 * W2, bv, nullptr, Vtb, 1.0f);
    attn_k<<<dim3(768), 256, 0, stream>>>(Qb, Kb, Vtb, attnw, Cb);
    gemm_mfma_k<0><<<gg, 256, 0, stream>>>(Cb, Wt + 3 * W2, bo, out0, nullptr, 1.0f);
}